// Round 5
// baseline (347.045 us; speedup 1.0000x reference)
//
#include <hip/hip_runtime.h>
#include <math.h>

#define N_NODES_C 100000
#define N_EDGES_C 1600000
#define DIM 64
#define G3 192
#define SCAN_B 1024
#define N_SCAN_BLOCKS ((N_NODES_C + SCAN_B - 1) / SCAN_B)   // 98

// ---------------------------------------------------------------------------
// Phase 1a: histogram receivers, record per-edge rank within its segment
// ---------------------------------------------------------------------------
__global__ void hist_kernel(const int* __restrict__ receivers,
                            int* __restrict__ count,
                            int* __restrict__ rank) {
    int e = blockIdx.x * blockDim.x + threadIdx.x;
    if (e >= N_EDGES_C) return;
    int r = receivers[e];
    rank[e] = __hip_atomic_fetch_add(&count[r], 1,
                                     __ATOMIC_RELAXED, __HIP_MEMORY_SCOPE_AGENT);
}

// ---------------------------------------------------------------------------
// Phase 1b: scan. offsets[] = block-local exclusive; bsums[] = per-block
// exclusive base (applied inline by consumers).
// ---------------------------------------------------------------------------
__global__ void scan1_kernel(const int* __restrict__ count,
                             int* __restrict__ offsets,
                             int* __restrict__ bsums) {
    __shared__ int wsum[16];
    const int gid  = blockIdx.x * SCAN_B + threadIdx.x;
    const int lane = threadIdx.x & 63;
    const int wv   = threadIdx.x >> 6;
    int c = (gid < N_NODES_C) ? count[gid] : 0;
    int x = c;
    #pragma unroll
    for (int o = 1; o < 64; o <<= 1) {
        int v = __shfl_up(x, o);
        if (lane >= o) x += v;
    }
    if (lane == 63) wsum[wv] = x;
    __syncthreads();
    if (wv == 0) {
        int s = (lane < 16) ? wsum[lane] : 0;
        #pragma unroll
        for (int o = 1; o < 16; o <<= 1) {
            int v = __shfl_up(s, o);
            if (lane >= o) s += v;
        }
        if (lane < 16) wsum[lane] = s;   // inclusive over waves
    }
    __syncthreads();
    int woff = (wv == 0) ? 0 : wsum[wv - 1];
    if (gid < N_NODES_C) offsets[gid] = woff + x - c;
    if (threadIdx.x == SCAN_B - 1) bsums[blockIdx.x] = wsum[15];
}

__global__ void scan2_kernel(int* __restrict__ bsums) {
    __shared__ int w0tot;
    const int i    = threadIdx.x;
    const int lane = threadIdx.x & 63;
    const int wv   = threadIdx.x >> 6;
    int c = (i < N_SCAN_BLOCKS) ? bsums[i] : 0;
    int x = c;
    #pragma unroll
    for (int o = 1; o < 64; o <<= 1) {
        int v = __shfl_up(x, o);
        if (lane >= o) x += v;
    }
    if (wv == 0 && lane == 63) w0tot = x;
    __syncthreads();
    int add = (wv == 1) ? w0tot : 0;
    if (i < N_SCAN_BLOCKS) bsums[i] = add + x - c;   // exclusive
}

// ---------------------------------------------------------------------------
// Phase 1c: write permutation (CSR edge lists); bsums applied inline
// ---------------------------------------------------------------------------
__global__ void permw_kernel(const int* __restrict__ receivers,
                             const int* __restrict__ offsets,
                             const int* __restrict__ bsums,
                             const int* __restrict__ rank,
                             int* __restrict__ perm) {
    int e = blockIdx.x * blockDim.x + threadIdx.x;
    if (e >= N_EDGES_C) return;
    int r = receivers[e];
    perm[offsets[r] + bsums[r >> 10] + rank[e]] = e;
}

// ---------------------------------------------------------------------------
// Phase 2: gather-aggregate, float4-widened. One wave per node.
// Lane L owns columns 4*(L&15)..+3 and row-group g = L>>4. One load
// instruction fetches 4 rows (1KB/wave); 8 chains = 32 rows/iter, 8KB in
// flight per wave. Cross-group reduce via shfl_xor(16,32); lanes 0-15 store.
// ---------------------------------------------------------------------------
#define NCH 8

__global__ __launch_bounds__(256)
void gather_kernel(const float* __restrict__ edges,
                   const int* __restrict__ perm,
                   const int* __restrict__ offsets,
                   const int* __restrict__ bsums,
                   const int* __restrict__ count,
                   float* __restrict__ aggr) {
    const int w    = (blockIdx.x << 2) | (threadIdx.x >> 6);
    const int lane = threadIdx.x & 63;
    if (w >= N_NODES_C) return;
    const int g    = lane >> 4;        // row-group 0..3
    const int c4   = (lane & 15) << 2; // column base
    const int start = offsets[w] + bsums[w >> 10];
    const int cnt   = count[w];

    float4 acc[NCH];
    #pragma unroll
    for (int ch = 0; ch < NCH; ++ch) acc[ch] = make_float4(0.f, 0.f, 0.f, 0.f);

    int done = 0;
    while (done < cnt) {
        #pragma unroll
        for (int ch = 0; ch < NCH; ++ch) {
            const int base = done + (ch << 2);
            if (base < cnt) {                       // wave-uniform guard
                const int row = base + g;           // per-lane row
                if (row < cnt) {                    // partial-group predicate
                    const int e = perm[start + row];
                    const float4 v = *reinterpret_cast<const float4*>(
                        edges + (size_t)e * DIM + c4);
                    acc[ch].x += v.x; acc[ch].y += v.y;
                    acc[ch].z += v.z; acc[ch].w += v.w;
                }
            }
        }
        done += NCH * 4;
    }

    // combine chains
    float4 s = acc[0];
    #pragma unroll
    for (int ch = 1; ch < NCH; ++ch) {
        s.x += acc[ch].x; s.y += acc[ch].y; s.z += acc[ch].z; s.w += acc[ch].w;
    }
    // cross-group reduction (groups 0..3 hold partials of the same columns)
    #pragma unroll
    for (int m = 16; m <= 32; m <<= 1) {
        s.x += __shfl_xor(s.x, m);
        s.y += __shfl_xor(s.y, m);
        s.z += __shfl_xor(s.z, m);
        s.w += __shfl_xor(s.w, m);
    }
    if (lane < 16) {
        *reinterpret_cast<float4*>(aggr + (size_t)w * DIM + c4) = s;
    }
}

// ---------------------------------------------------------------------------
// Phase 3: GRU cell update. Block = 256 threads / 32 nodes. aggr_out (=d_out)
// is read (32 rows staged to LDS) then overwritten with the result.
// ---------------------------------------------------------------------------
#define NT 32
#define NPW 8
#define WPAD 68   // padded row stride (floats); 272B, 16B-aligned

__global__ __launch_bounds__(256, 2)
void gru_kernel(float* aggr_out,
                const float* __restrict__ nodes,
                const float* __restrict__ w_ih,
                const float* __restrict__ w_hh,
                const float* __restrict__ b_ih,
                const float* __restrict__ b_hh) {
    __shared__ float wlds[G3 * WPAD];   // 52.2 KB
    __shared__ float rows[NT * DIM];    // 8 KB

    const int tid  = threadIdx.x;
    const int lane = tid & 63;
    const int wave = tid >> 6;
    const int nb   = blockIdx.x * NT;
    const int myn0 = wave * NPW;

    float accA[NPW][3];
    float accB[NPW][3];

    // ---- stage w_ih + this block's aggr rows
    {
        const float4* src = reinterpret_cast<const float4*>(w_ih);
        #pragma unroll
        for (int i = 0; i < 12; ++i) {
            int t = tid + i * 256;               // 3072 float4s
            float4 v = src[t];
            int row = t >> 4;
            int col = (t & 15) << 2;
            *reinterpret_cast<float4*>(&wlds[row * WPAD + col]) = v;
        }
        #pragma unroll
        for (int i = 0; i < 2; ++i) {
            int t = tid + i * 256;               // 512 float4s
            int n = t >> 4, c = (t & 15) << 2;
            *reinterpret_cast<float4*>(&rows[n * DIM + c]) =
                *reinterpret_cast<const float4*>(&aggr_out[(size_t)(nb + n) * DIM + c]);
        }
    }
    __syncthreads();

    // ---- pass A: gi = aggr @ w_ih.T
    #pragma unroll
    for (int n = 0; n < NPW; ++n) { accA[n][0] = 0.f; accA[n][1] = 0.f; accA[n][2] = 0.f; }
    #pragma unroll 4
    for (int ks = 0; ks < 16; ++ks) {
        const int k = ks * 4;
        float4 wr = *reinterpret_cast<const float4*>(&wlds[lane * WPAD + k]);
        float4 wz = *reinterpret_cast<const float4*>(&wlds[(64 + lane) * WPAD + k]);
        float4 wn = *reinterpret_cast<const float4*>(&wlds[(128 + lane) * WPAD + k]);
        #pragma unroll
        for (int n = 0; n < NPW; ++n) {
            float4 a = *reinterpret_cast<const float4*>(&rows[(myn0 + n) * DIM + k]);
            accA[n][0] += a.x * wr.x + a.y * wr.y + a.z * wr.z + a.w * wr.w;
            accA[n][1] += a.x * wz.x + a.y * wz.y + a.z * wz.z + a.w * wz.w;
            accA[n][2] += a.x * wn.x + a.y * wn.y + a.z * wn.z + a.w * wn.w;
        }
    }
    __syncthreads();

    // ---- restage: w_hh + node rows
    {
        const float4* src = reinterpret_cast<const float4*>(w_hh);
        #pragma unroll
        for (int i = 0; i < 12; ++i) {
            int t = tid + i * 256;
            float4 v = src[t];
            int row = t >> 4;
            int col = (t & 15) << 2;
            *reinterpret_cast<float4*>(&wlds[row * WPAD + col]) = v;
        }
        #pragma unroll
        for (int i = 0; i < 2; ++i) {
            int t = tid + i * 256;
            int n = t >> 4, c = (t & 15) << 2;
            *reinterpret_cast<float4*>(&rows[n * DIM + c]) =
                *reinterpret_cast<const float4*>(&nodes[(size_t)(nb + n) * DIM + c]);
        }
    }
    __syncthreads();

    // ---- pass B: gh = nodes @ w_hh.T
    #pragma unroll
    for (int n = 0; n < NPW; ++n) { accB[n][0] = 0.f; accB[n][1] = 0.f; accB[n][2] = 0.f; }
    #pragma unroll 4
    for (int ks = 0; ks < 16; ++ks) {
        const int k = ks * 4;
        float4 wr = *reinterpret_cast<const float4*>(&wlds[lane * WPAD + k]);
        float4 wz = *reinterpret_cast<const float4*>(&wlds[(64 + lane) * WPAD + k]);
        float4 wn = *reinterpret_cast<const float4*>(&wlds[(128 + lane) * WPAD + k]);
        #pragma unroll
        for (int n = 0; n < NPW; ++n) {
            float4 a = *reinterpret_cast<const float4*>(&rows[(myn0 + n) * DIM + k]);
            accB[n][0] += a.x * wr.x + a.y * wr.y + a.z * wr.z + a.w * wr.w;
            accB[n][1] += a.x * wz.x + a.y * wz.y + a.z * wz.z + a.w * wz.w;
            accB[n][2] += a.x * wn.x + a.y * wn.y + a.z * wn.z + a.w * wn.w;
        }
    }

    // ---- gates + output (overwrite aggr_out)
    const float bir = b_ih[lane], biz = b_ih[64 + lane], bin_ = b_ih[128 + lane];
    const float bhr = b_hh[lane], bhz = b_hh[64 + lane], bhn = b_hh[128 + lane];
    #pragma unroll
    for (int n = 0; n < NPW; ++n) {
        const int node = nb + myn0 + n;
        const float h = rows[(myn0 + n) * DIM + lane];   // rows holds `nodes`
        const float ir = accA[n][0] + bir, iz = accA[n][1] + biz, inn = accA[n][2] + bin_;
        const float hr = accB[n][0] + bhr, hz = accB[n][1] + bhz, hn = accB[n][2] + bhn;
        const float r = 1.f / (1.f + __expf(-(ir + hr)));
        const float z = 1.f / (1.f + __expf(-(iz + hz)));
        float t = inn + r * hn;
        t = fminf(fmaxf(t, -15.f), 15.f);
        const float e2 = __expf(2.f * t);
        const float ng = (e2 - 1.f) / (e2 + 1.f);
        aggr_out[(size_t)node * DIM + lane] = (1.f - z) * ng + z * h;
    }
}

// ---------------------------------------------------------------------------
extern "C" void kernel_launch(void* const* d_in, const int* in_sizes, int n_in,
                              void* d_out, int out_size, void* d_ws, size_t ws_size,
                              hipStream_t stream) {
    const float* edges     = (const float*)d_in[0];
    const float* nodes     = (const float*)d_in[1];
    const int*   receivers = (const int*)d_in[2];
    const float* w_ih      = (const float*)d_in[3];
    const float* w_hh      = (const float*)d_in[4];
    const float* b_ih      = (const float*)d_in[5];
    const float* b_hh      = (const float*)d_in[6];
    float* out = (float*)d_out;

    // workspace layout (ints, ~13.6 MB)
    int* ws      = (int*)d_ws;
    int* count   = ws;                       // 100000
    int* offsets = ws + N_NODES_C;           // 100000
    int* rank    = ws + 2 * N_NODES_C;       // 1.6M
    int* perm    = rank + N_EDGES_C;         // 1.6M
    int* bsums   = perm + N_EDGES_C;         // 128

    hipMemsetAsync(count, 0, N_NODES_C * sizeof(int), stream);

    hist_kernel<<<(N_EDGES_C + 255) / 256, 256, 0, stream>>>(receivers, count, rank);
    scan1_kernel<<<N_SCAN_BLOCKS, SCAN_B, 0, stream>>>(count, offsets, bsums);
    scan2_kernel<<<1, 128, 0, stream>>>(bsums);
    permw_kernel<<<(N_EDGES_C + 255) / 256, 256, 0, stream>>>(receivers, offsets, bsums, rank, perm);

    // aggr lives in d_out; gru_kernel consumes and overwrites it in place.
    gather_kernel<<<(N_NODES_C + 3) / 4, 256, 0, stream>>>(edges, perm, offsets, bsums, count, out);
    gru_kernel<<<N_NODES_C / NT, 256, 0, stream>>>(out, nodes, w_ih, w_hh, b_ih, b_hh);
}

// Round 6
// 334.040 us; speedup vs baseline: 1.0389x; 1.0389x over previous
//
#include <hip/hip_runtime.h>
#include <math.h>

#define N_NODES_C 100000
#define N_EDGES_C 1600000
#define DIM 64
#define G3 192
#define SCAN_B 1024
#define N_SCAN_BLOCKS ((N_NODES_C + SCAN_B - 1) / SCAN_B)   // 98

// ---------------------------------------------------------------------------
// Phase 1a: histogram receivers, record per-edge rank within its segment
// ---------------------------------------------------------------------------
__global__ void hist_kernel(const int* __restrict__ receivers,
                            int* __restrict__ count,
                            int* __restrict__ rank) {
    int e = blockIdx.x * blockDim.x + threadIdx.x;
    if (e >= N_EDGES_C) return;
    int r = receivers[e];
    rank[e] = __hip_atomic_fetch_add(&count[r], 1,
                                     __ATOMIC_RELAXED, __HIP_MEMORY_SCOPE_AGENT);
}

// ---------------------------------------------------------------------------
// Phase 1b: scan. offsets[] = block-local exclusive; bsums[] = per-block
// exclusive base (applied inline by consumers).
// ---------------------------------------------------------------------------
__global__ void scan1_kernel(const int* __restrict__ count,
                             int* __restrict__ offsets,
                             int* __restrict__ bsums) {
    __shared__ int wsum[16];
    const int gid  = blockIdx.x * SCAN_B + threadIdx.x;
    const int lane = threadIdx.x & 63;
    const int wv   = threadIdx.x >> 6;
    int c = (gid < N_NODES_C) ? count[gid] : 0;
    int x = c;
    #pragma unroll
    for (int o = 1; o < 64; o <<= 1) {
        int v = __shfl_up(x, o);
        if (lane >= o) x += v;
    }
    if (lane == 63) wsum[wv] = x;
    __syncthreads();
    if (wv == 0) {
        int s = (lane < 16) ? wsum[lane] : 0;
        #pragma unroll
        for (int o = 1; o < 16; o <<= 1) {
            int v = __shfl_up(s, o);
            if (lane >= o) s += v;
        }
        if (lane < 16) wsum[lane] = s;   // inclusive over waves
    }
    __syncthreads();
    int woff = (wv == 0) ? 0 : wsum[wv - 1];
    if (gid < N_NODES_C) offsets[gid] = woff + x - c;
    if (threadIdx.x == SCAN_B - 1) bsums[blockIdx.x] = wsum[15];
}

__global__ void scan2_kernel(int* __restrict__ bsums) {
    __shared__ int w0tot;
    const int i    = threadIdx.x;
    const int lane = threadIdx.x & 63;
    const int wv   = threadIdx.x >> 6;
    int c = (i < N_SCAN_BLOCKS) ? bsums[i] : 0;
    int x = c;
    #pragma unroll
    for (int o = 1; o < 64; o <<= 1) {
        int v = __shfl_up(x, o);
        if (lane >= o) x += v;
    }
    if (wv == 0 && lane == 63) w0tot = x;
    __syncthreads();
    int add = (wv == 1) ? w0tot : 0;
    if (i < N_SCAN_BLOCKS) bsums[i] = add + x - c;   // exclusive
}

// ---------------------------------------------------------------------------
// Phase 1c: write permutation (CSR edge lists); bsums applied inline
// ---------------------------------------------------------------------------
__global__ void permw_kernel(const int* __restrict__ receivers,
                             const int* __restrict__ offsets,
                             const int* __restrict__ bsums,
                             const int* __restrict__ rank,
                             int* __restrict__ perm) {
    int e = blockIdx.x * blockDim.x + threadIdx.x;
    if (e >= N_EDGES_C) return;
    int r = receivers[e];
    perm[offsets[r] + bsums[r >> 10] + rank[e]] = e;
}

// ---------------------------------------------------------------------------
// Phase 2: gather-aggregate (round-4 form). One wave per node; perm segment
// loaded with one coalesced vector load, indices extracted via readlane.
// ---------------------------------------------------------------------------
__global__ __launch_bounds__(256)
void gather_kernel(const float* __restrict__ edges,
                   const int* __restrict__ perm,
                   const int* __restrict__ offsets,
                   const int* __restrict__ bsums,
                   const int* __restrict__ count,
                   float* __restrict__ aggr) {
    const int w    = (blockIdx.x << 2) | (threadIdx.x >> 6);
    const int lane = threadIdx.x & 63;
    if (w >= N_NODES_C) return;
    const int start = offsets[w] + bsums[w >> 10];
    const int cnt   = count[w];

    float a0 = 0.f, a1 = 0.f, a2 = 0.f, a3 = 0.f;
    float a4 = 0.f, a5 = 0.f, a6 = 0.f, a7 = 0.f;

    int done = 0;
    while (done < cnt) {
        const int chunk = min(cnt - done, 64);
        int pv = 0;
        if (lane < chunk) pv = perm[start + done + lane];
        int i = 0;
        for (; i + 8 <= chunk; i += 8) {
            const int e0 = __builtin_amdgcn_readlane(pv, i + 0);
            const int e1 = __builtin_amdgcn_readlane(pv, i + 1);
            const int e2 = __builtin_amdgcn_readlane(pv, i + 2);
            const int e3 = __builtin_amdgcn_readlane(pv, i + 3);
            const int e4 = __builtin_amdgcn_readlane(pv, i + 4);
            const int e5 = __builtin_amdgcn_readlane(pv, i + 5);
            const int e6 = __builtin_amdgcn_readlane(pv, i + 6);
            const int e7 = __builtin_amdgcn_readlane(pv, i + 7);
            a0 += edges[(size_t)e0 * DIM + lane];
            a1 += edges[(size_t)e1 * DIM + lane];
            a2 += edges[(size_t)e2 * DIM + lane];
            a3 += edges[(size_t)e3 * DIM + lane];
            a4 += edges[(size_t)e4 * DIM + lane];
            a5 += edges[(size_t)e5 * DIM + lane];
            a6 += edges[(size_t)e6 * DIM + lane];
            a7 += edges[(size_t)e7 * DIM + lane];
        }
        if (i + 4 <= chunk) {
            const int e0 = __builtin_amdgcn_readlane(pv, i + 0);
            const int e1 = __builtin_amdgcn_readlane(pv, i + 1);
            const int e2 = __builtin_amdgcn_readlane(pv, i + 2);
            const int e3 = __builtin_amdgcn_readlane(pv, i + 3);
            a0 += edges[(size_t)e0 * DIM + lane];
            a1 += edges[(size_t)e1 * DIM + lane];
            a2 += edges[(size_t)e2 * DIM + lane];
            a3 += edges[(size_t)e3 * DIM + lane];
            i += 4;
        }
        if (i + 2 <= chunk) {
            const int e0 = __builtin_amdgcn_readlane(pv, i + 0);
            const int e1 = __builtin_amdgcn_readlane(pv, i + 1);
            a4 += edges[(size_t)e0 * DIM + lane];
            a5 += edges[(size_t)e1 * DIM + lane];
            i += 2;
        }
        if (i < chunk) {
            const int e0 = __builtin_amdgcn_readlane(pv, i);
            a6 += edges[(size_t)e0 * DIM + lane];
        }
        done += chunk;
    }
    aggr[(size_t)w * DIM + lane] = ((a0 + a1) + (a2 + a3)) + ((a4 + a5) + (a6 + a7));
}

// ---------------------------------------------------------------------------
// Phase 3: GRU cell update, v2. Block = 256 threads / NT=64 nodes, NPW=16
// nodes per lane (each weight fragment read from LDS feeds 16 nodes -> LDS
// port no longer the bottleneck). Weights stored UNPADDED [192][64] with an
// XOR swizzle on the 16B chunk index (chunk' = ks ^ (row&7)) so the strided
// ds_read_b128 stays at its 8-phase floor. LDS = 48KB + 16KB = 64KB exactly,
// 2 blocks/CU. aggr_out (=d_out) is read then overwritten with the result.
// ---------------------------------------------------------------------------
#define NT 64
#define NPW 16

__global__ __launch_bounds__(256, 2)
void gru_kernel(float* aggr_out,
                const float* __restrict__ nodes,
                const float* __restrict__ w_ih,
                const float* __restrict__ w_hh,
                const float* __restrict__ b_ih,
                const float* __restrict__ b_hh) {
    __shared__ float wlds[G3 * DIM];    // 48 KB, swizzled
    __shared__ float rows[NT * DIM];    // 16 KB

    const int tid  = threadIdx.x;
    const int lane = tid & 63;
    const int wave = tid >> 6;
    const int nb   = blockIdx.x * NT;
    const int myn0 = wave * NPW;

    float accA[NPW][3];
    float accB[NPW][3];

    const float4 zero4 = make_float4(0.f, 0.f, 0.f, 0.f);

    // ---- stage w_ih (swizzled) + this block's aggr rows (guarded)
    {
        const float4* src = reinterpret_cast<const float4*>(w_ih);
        #pragma unroll
        for (int i = 0; i < 12; ++i) {
            int t = tid + i * 256;               // 3072 float4s
            float4 v = src[t];
            int row = t >> 4;
            int ch  = (t & 15) ^ (row & 7);      // swizzled 16B-chunk index
            *reinterpret_cast<float4*>(&wlds[row * DIM + (ch << 2)]) = v;
        }
        #pragma unroll
        for (int i = 0; i < 4; ++i) {
            int t = tid + i * 256;               // 1024 float4s
            int n = t >> 4, c = (t & 15) << 2;
            float4 v = (nb + n < N_NODES_C)
                ? *reinterpret_cast<const float4*>(&aggr_out[(size_t)(nb + n) * DIM + c])
                : zero4;
            *reinterpret_cast<float4*>(&rows[n * DIM + c]) = v;
        }
    }
    __syncthreads();

    // ---- pass A: gi = aggr @ w_ih.T
    #pragma unroll
    for (int n = 0; n < NPW; ++n) { accA[n][0] = 0.f; accA[n][1] = 0.f; accA[n][2] = 0.f; }
    #pragma unroll 2
    for (int ks = 0; ks < 16; ++ks) {
        const int kw = ((ks ^ (lane & 7)) << 2);   // swizzled word offset in row
        const int k  = ks << 2;
        float4 wr = *reinterpret_cast<const float4*>(&wlds[lane * DIM + kw]);
        float4 wz = *reinterpret_cast<const float4*>(&wlds[(64 + lane) * DIM + kw]);
        float4 wn = *reinterpret_cast<const float4*>(&wlds[(128 + lane) * DIM + kw]);
        #pragma unroll
        for (int n = 0; n < NPW; ++n) {
            float4 a = *reinterpret_cast<const float4*>(&rows[(myn0 + n) * DIM + k]);
            accA[n][0] += a.x * wr.x + a.y * wr.y + a.z * wr.z + a.w * wr.w;
            accA[n][1] += a.x * wz.x + a.y * wz.y + a.z * wz.z + a.w * wz.w;
            accA[n][2] += a.x * wn.x + a.y * wn.y + a.z * wn.z + a.w * wn.w;
        }
    }
    __syncthreads();

    // ---- restage: w_hh (swizzled) + node rows (guarded)
    {
        const float4* src = reinterpret_cast<const float4*>(w_hh);
        #pragma unroll
        for (int i = 0; i < 12; ++i) {
            int t = tid + i * 256;
            float4 v = src[t];
            int row = t >> 4;
            int ch  = (t & 15) ^ (row & 7);
            *reinterpret_cast<float4*>(&wlds[row * DIM + (ch << 2)]) = v;
        }
        #pragma unroll
        for (int i = 0; i < 4; ++i) {
            int t = tid + i * 256;
            int n = t >> 4, c = (t & 15) << 2;
            float4 v = (nb + n < N_NODES_C)
                ? *reinterpret_cast<const float4*>(&nodes[(size_t)(nb + n) * DIM + c])
                : zero4;
            *reinterpret_cast<float4*>(&rows[n * DIM + c]) = v;
        }
    }
    __syncthreads();

    // ---- pass B: gh = nodes @ w_hh.T
    #pragma unroll
    for (int n = 0; n < NPW; ++n) { accB[n][0] = 0.f; accB[n][1] = 0.f; accB[n][2] = 0.f; }
    #pragma unroll 2
    for (int ks = 0; ks < 16; ++ks) {
        const int kw = ((ks ^ (lane & 7)) << 2);
        const int k  = ks << 2;
        float4 wr = *reinterpret_cast<const float4*>(&wlds[lane * DIM + kw]);
        float4 wz = *reinterpret_cast<const float4*>(&wlds[(64 + lane) * DIM + kw]);
        float4 wn = *reinterpret_cast<const float4*>(&wlds[(128 + lane) * DIM + kw]);
        #pragma unroll
        for (int n = 0; n < NPW; ++n) {
            float4 a = *reinterpret_cast<const float4*>(&rows[(myn0 + n) * DIM + k]);
            accB[n][0] += a.x * wr.x + a.y * wr.y + a.z * wr.z + a.w * wr.w;
            accB[n][1] += a.x * wz.x + a.y * wz.y + a.z * wz.z + a.w * wz.w;
            accB[n][2] += a.x * wn.x + a.y * wn.y + a.z * wn.z + a.w * wn.w;
        }
    }

    // ---- gates + output (overwrite aggr_out)
    const float bir = b_ih[lane], biz = b_ih[64 + lane], bin_ = b_ih[128 + lane];
    const float bhr = b_hh[lane], bhz = b_hh[64 + lane], bhn = b_hh[128 + lane];
    #pragma unroll
    for (int n = 0; n < NPW; ++n) {
        const int node = nb + myn0 + n;
        if (node >= N_NODES_C) break;
        const float h = rows[(myn0 + n) * DIM + lane];   // rows holds `nodes`
        const float ir = accA[n][0] + bir, iz = accA[n][1] + biz, inn = accA[n][2] + bin_;
        const float hr = accB[n][0] + bhr, hz = accB[n][1] + bhz, hn = accB[n][2] + bhn;
        const float r = 1.f / (1.f + __expf(-(ir + hr)));
        const float z = 1.f / (1.f + __expf(-(iz + hz)));
        float t = inn + r * hn;
        t = fminf(fmaxf(t, -15.f), 15.f);
        const float e2 = __expf(2.f * t);
        const float ng = (e2 - 1.f) / (e2 + 1.f);
        aggr_out[(size_t)node * DIM + lane] = (1.f - z) * ng + z * h;
    }
}

// ---------------------------------------------------------------------------
extern "C" void kernel_launch(void* const* d_in, const int* in_sizes, int n_in,
                              void* d_out, int out_size, void* d_ws, size_t ws_size,
                              hipStream_t stream) {
    const float* edges     = (const float*)d_in[0];
    const float* nodes     = (const float*)d_in[1];
    const int*   receivers = (const int*)d_in[2];
    const float* w_ih      = (const float*)d_in[3];
    const float* w_hh      = (const float*)d_in[4];
    const float* b_ih      = (const float*)d_in[5];
    const float* b_hh      = (const float*)d_in[6];
    float* out = (float*)d_out;

    // workspace layout (ints, ~13.6 MB)
    int* ws      = (int*)d_ws;
    int* count   = ws;                       // 100000
    int* offsets = ws + N_NODES_C;           // 100000
    int* rank    = ws + 2 * N_NODES_C;       // 1.6M
    int* perm    = rank + N_EDGES_C;         // 1.6M
    int* bsums   = perm + N_EDGES_C;         // 128

    hipMemsetAsync(count, 0, N_NODES_C * sizeof(int), stream);

    hist_kernel<<<(N_EDGES_C + 255) / 256, 256, 0, stream>>>(receivers, count, rank);
    scan1_kernel<<<N_SCAN_BLOCKS, SCAN_B, 0, stream>>>(count, offsets, bsums);
    scan2_kernel<<<1, 128, 0, stream>>>(bsums);
    permw_kernel<<<(N_EDGES_C + 255) / 256, 256, 0, stream>>>(receivers, offsets, bsums, rank, perm);

    // aggr lives in d_out; gru_kernel consumes and overwrites it in place.
    gather_kernel<<<(N_NODES_C + 3) / 4, 256, 0, stream>>>(edges, perm, offsets, bsums, count, out);
    gru_kernel<<<(N_NODES_C + NT - 1) / NT, 256, 0, stream>>>(out, nodes, w_ih, w_hh, b_ih, b_hh);
}

// Round 7
// 323.395 us; speedup vs baseline: 1.0731x; 1.0329x over previous
//
#include <hip/hip_runtime.h>
#include <math.h>

#define N_NODES_C 100000
#define N_EDGES_C 1600000
#define DIM 64
#define G3 192
#define SCAN_B 1024
#define N_SCAN_BLOCKS ((N_NODES_C + SCAN_B - 1) / SCAN_B)   // 98

// ---------------------------------------------------------------------------
// Phase 1a: histogram receivers, record per-edge rank within its segment
// ---------------------------------------------------------------------------
__global__ void hist_kernel(const int* __restrict__ receivers,
                            int* __restrict__ count,
                            int* __restrict__ rank) {
    int e = blockIdx.x * blockDim.x + threadIdx.x;
    if (e >= N_EDGES_C) return;
    int r = receivers[e];
    rank[e] = __hip_atomic_fetch_add(&count[r], 1,
                                     __ATOMIC_RELAXED, __HIP_MEMORY_SCOPE_AGENT);
}

// ---------------------------------------------------------------------------
// Phase 1b: scan. offsets[] = block-local exclusive; bsums[] = per-block
// exclusive base (applied inline by consumers).
// ---------------------------------------------------------------------------
__global__ void scan1_kernel(const int* __restrict__ count,
                             int* __restrict__ offsets,
                             int* __restrict__ bsums) {
    __shared__ int wsum[16];
    const int gid  = blockIdx.x * SCAN_B + threadIdx.x;
    const int lane = threadIdx.x & 63;
    const int wv   = threadIdx.x >> 6;
    int c = (gid < N_NODES_C) ? count[gid] : 0;
    int x = c;
    #pragma unroll
    for (int o = 1; o < 64; o <<= 1) {
        int v = __shfl_up(x, o);
        if (lane >= o) x += v;
    }
    if (lane == 63) wsum[wv] = x;
    __syncthreads();
    if (wv == 0) {
        int s = (lane < 16) ? wsum[lane] : 0;
        #pragma unroll
        for (int o = 1; o < 16; o <<= 1) {
            int v = __shfl_up(s, o);
            if (lane >= o) s += v;
        }
        if (lane < 16) wsum[lane] = s;   // inclusive over waves
    }
    __syncthreads();
    int woff = (wv == 0) ? 0 : wsum[wv - 1];
    if (gid < N_NODES_C) offsets[gid] = woff + x - c;
    if (threadIdx.x == SCAN_B - 1) bsums[blockIdx.x] = wsum[15];
}

__global__ void scan2_kernel(int* __restrict__ bsums) {
    __shared__ int w0tot;
    const int i    = threadIdx.x;
    const int lane = threadIdx.x & 63;
    const int wv   = threadIdx.x >> 6;
    int c = (i < N_SCAN_BLOCKS) ? bsums[i] : 0;
    int x = c;
    #pragma unroll
    for (int o = 1; o < 64; o <<= 1) {
        int v = __shfl_up(x, o);
        if (lane >= o) x += v;
    }
    if (wv == 0 && lane == 63) w0tot = x;
    __syncthreads();
    int add = (wv == 1) ? w0tot : 0;
    if (i < N_SCAN_BLOCKS) bsums[i] = add + x - c;   // exclusive
}

// ---------------------------------------------------------------------------
// Phase 1c: write permutation (CSR edge lists); bsums applied inline
// ---------------------------------------------------------------------------
__global__ void permw_kernel(const int* __restrict__ receivers,
                             const int* __restrict__ offsets,
                             const int* __restrict__ bsums,
                             const int* __restrict__ rank,
                             int* __restrict__ perm) {
    int e = blockIdx.x * blockDim.x + threadIdx.x;
    if (e >= N_EDGES_C) return;
    int r = receivers[e];
    perm[offsets[r] + bsums[r >> 10] + rank[e]] = e;
}

// ---------------------------------------------------------------------------
// Phase 2: gather-aggregate, float4-wide + branchless masking. One wave per
// node. Lane L = group g=L>>4 (row within 4-row burst) x column c4=(L&15)*4.
// Per 64-row window: ONE coalesced perm segment load, then up to 4 groups of
// 4 bursts; each burst is one float4 load covering 4 rows (1KB/instr, 4KB in
// flight per group). OOB rows are clamped to cnt-1 (L2-hot) and masked with
// a 0/1 multiplier -> no per-load branches. Cross-group shfl_xor reduce.
// ---------------------------------------------------------------------------
__global__ __launch_bounds__(256)
void gather_kernel(const float* __restrict__ edges,
                   const int* __restrict__ perm,
                   const int* __restrict__ offsets,
                   const int* __restrict__ bsums,
                   const int* __restrict__ count,
                   float* __restrict__ aggr) {
    const int w    = (blockIdx.x << 2) | (threadIdx.x >> 6);
    const int lane = threadIdx.x & 63;
    if (w >= N_NODES_C) return;
    const int g    = lane >> 4;        // row-in-burst 0..3
    const int c4   = (lane & 15) << 2; // column base
    const int start = offsets[w] + bsums[w >> 10];
    const int cnt   = count[w];

    float4 a0 = make_float4(0.f, 0.f, 0.f, 0.f);
    float4 a1 = a0, a2 = a0, a3 = a0;

    int done = 0;
    while (done < cnt) {
        // one coalesced load of this 64-row window of perm (clamped)
        const int pv  = perm[start + min(done + lane, cnt - 1)];
        const int lim = min(cnt - done, 64);       // rows in this window
        const int nq  = (lim + 15) >> 4;           // 4-burst groups, 1..4
        for (int q = 0; q < nq; ++q) {             // wave-uniform trip count
            const int rbase = q << 4;
            #pragma unroll
            for (int b = 0; b < 4; ++b) {
                const int rr  = rbase + (b << 2) + g;     // row in window
                const int src = min(rr, lim - 1);         // clamped shfl idx
                const int e   = __shfl(pv, src);
                const float4 v = *reinterpret_cast<const float4*>(
                    edges + (size_t)e * DIM + c4);
                const float m = (rr < lim) ? 1.f : 0.f;
                if (b == 0) { a0.x += v.x*m; a0.y += v.y*m; a0.z += v.z*m; a0.w += v.w*m; }
                if (b == 1) { a1.x += v.x*m; a1.y += v.y*m; a1.z += v.z*m; a1.w += v.w*m; }
                if (b == 2) { a2.x += v.x*m; a2.y += v.y*m; a2.z += v.z*m; a2.w += v.w*m; }
                if (b == 3) { a3.x += v.x*m; a3.y += v.y*m; a3.z += v.z*m; a3.w += v.w*m; }
            }
        }
        done += 64;
    }

    float4 s;
    s.x = (a0.x + a1.x) + (a2.x + a3.x);
    s.y = (a0.y + a1.y) + (a2.y + a3.y);
    s.z = (a0.z + a1.z) + (a2.z + a3.z);
    s.w = (a0.w + a1.w) + (a2.w + a3.w);
    #pragma unroll
    for (int m = 16; m <= 32; m <<= 1) {
        s.x += __shfl_xor(s.x, m);
        s.y += __shfl_xor(s.y, m);
        s.z += __shfl_xor(s.z, m);
        s.w += __shfl_xor(s.w, m);
    }
    if (lane < 16) {
        *reinterpret_cast<float4*>(aggr + (size_t)w * DIM + c4) = s;
    }
}

// ---------------------------------------------------------------------------
// Phase 3: GRU cell update (round-4 form). Block = 256 threads / 32 nodes.
// aggr_out (=d_out) is read (32 rows staged to LDS) then overwritten.
// ---------------------------------------------------------------------------
#define NT 32
#define NPW 8
#define WPAD 68   // padded row stride (floats); 272B, 16B-aligned

__global__ __launch_bounds__(256, 2)
void gru_kernel(float* aggr_out,
                const float* __restrict__ nodes,
                const float* __restrict__ w_ih,
                const float* __restrict__ w_hh,
                const float* __restrict__ b_ih,
                const float* __restrict__ b_hh) {
    __shared__ float wlds[G3 * WPAD];   // 52.2 KB
    __shared__ float rows[NT * DIM];    // 8 KB

    const int tid  = threadIdx.x;
    const int lane = tid & 63;
    const int wave = tid >> 6;
    const int nb   = blockIdx.x * NT;
    const int myn0 = wave * NPW;

    float accA[NPW][3];
    float accB[NPW][3];

    // ---- stage w_ih + this block's aggr rows
    {
        const float4* src = reinterpret_cast<const float4*>(w_ih);
        #pragma unroll
        for (int i = 0; i < 12; ++i) {
            int t = tid + i * 256;               // 3072 float4s
            float4 v = src[t];
            int row = t >> 4;
            int col = (t & 15) << 2;
            *reinterpret_cast<float4*>(&wlds[row * WPAD + col]) = v;
        }
        #pragma unroll
        for (int i = 0; i < 2; ++i) {
            int t = tid + i * 256;               // 512 float4s
            int n = t >> 4, c = (t & 15) << 2;
            *reinterpret_cast<float4*>(&rows[n * DIM + c]) =
                *reinterpret_cast<const float4*>(&aggr_out[(size_t)(nb + n) * DIM + c]);
        }
    }
    __syncthreads();

    // ---- pass A: gi = aggr @ w_ih.T
    #pragma unroll
    for (int n = 0; n < NPW; ++n) { accA[n][0] = 0.f; accA[n][1] = 0.f; accA[n][2] = 0.f; }
    #pragma unroll 4
    for (int ks = 0; ks < 16; ++ks) {
        const int k = ks * 4;
        float4 wr = *reinterpret_cast<const float4*>(&wlds[lane * WPAD + k]);
        float4 wz = *reinterpret_cast<const float4*>(&wlds[(64 + lane) * WPAD + k]);
        float4 wn = *reinterpret_cast<const float4*>(&wlds[(128 + lane) * WPAD + k]);
        #pragma unroll
        for (int n = 0; n < NPW; ++n) {
            float4 a = *reinterpret_cast<const float4*>(&rows[(myn0 + n) * DIM + k]);
            accA[n][0] += a.x * wr.x + a.y * wr.y + a.z * wr.z + a.w * wr.w;
            accA[n][1] += a.x * wz.x + a.y * wz.y + a.z * wz.z + a.w * wz.w;
            accA[n][2] += a.x * wn.x + a.y * wn.y + a.z * wn.z + a.w * wn.w;
        }
    }
    __syncthreads();

    // ---- restage: w_hh + node rows
    {
        const float4* src = reinterpret_cast<const float4*>(w_hh);
        #pragma unroll
        for (int i = 0; i < 12; ++i) {
            int t = tid + i * 256;
            float4 v = src[t];
            int row = t >> 4;
            int col = (t & 15) << 2;
            *reinterpret_cast<float4*>(&wlds[row * WPAD + col]) = v;
        }
        #pragma unroll
        for (int i = 0; i < 2; ++i) {
            int t = tid + i * 256;
            int n = t >> 4, c = (t & 15) << 2;
            *reinterpret_cast<float4*>(&rows[n * DIM + c]) =
                *reinterpret_cast<const float4*>(&nodes[(size_t)(nb + n) * DIM + c]);
        }
    }
    __syncthreads();

    // ---- pass B: gh = nodes @ w_hh.T
    #pragma unroll
    for (int n = 0; n < NPW; ++n) { accB[n][0] = 0.f; accB[n][1] = 0.f; accB[n][2] = 0.f; }
    #pragma unroll 4
    for (int ks = 0; ks < 16; ++ks) {
        const int k = ks * 4;
        float4 wr = *reinterpret_cast<const float4*>(&wlds[lane * WPAD + k]);
        float4 wz = *reinterpret_cast<const float4*>(&wlds[(64 + lane) * WPAD + k]);
        float4 wn = *reinterpret_cast<const float4*>(&wlds[(128 + lane) * WPAD + k]);
        #pragma unroll
        for (int n = 0; n < NPW; ++n) {
            float4 a = *reinterpret_cast<const float4*>(&rows[(myn0 + n) * DIM + k]);
            accB[n][0] += a.x * wr.x + a.y * wr.y + a.z * wr.z + a.w * wr.w;
            accB[n][1] += a.x * wz.x + a.y * wz.y + a.z * wz.z + a.w * wz.w;
            accB[n][2] += a.x * wn.x + a.y * wn.y + a.z * wn.z + a.w * wn.w;
        }
    }

    // ---- gates + output (overwrite aggr_out)
    const float bir = b_ih[lane], biz = b_ih[64 + lane], bin_ = b_ih[128 + lane];
    const float bhr = b_hh[lane], bhz = b_hh[64 + lane], bhn = b_hh[128 + lane];
    #pragma unroll
    for (int n = 0; n < NPW; ++n) {
        const int node = nb + myn0 + n;
        const float h = rows[(myn0 + n) * DIM + lane];   // rows holds `nodes`
        const float ir = accA[n][0] + bir, iz = accA[n][1] + biz, inn = accA[n][2] + bin_;
        const float hr = accB[n][0] + bhr, hz = accB[n][1] + bhz, hn = accB[n][2] + bhn;
        const float r = 1.f / (1.f + __expf(-(ir + hr)));
        const float z = 1.f / (1.f + __expf(-(iz + hz)));
        float t = inn + r * hn;
        t = fminf(fmaxf(t, -15.f), 15.f);
        const float e2 = __expf(2.f * t);
        const float ng = (e2 - 1.f) / (e2 + 1.f);
        aggr_out[(size_t)node * DIM + lane] = (1.f - z) * ng + z * h;
    }
}

// ---------------------------------------------------------------------------
extern "C" void kernel_launch(void* const* d_in, const int* in_sizes, int n_in,
                              void* d_out, int out_size, void* d_ws, size_t ws_size,
                              hipStream_t stream) {
    const float* edges     = (const float*)d_in[0];
    const float* nodes     = (const float*)d_in[1];
    const int*   receivers = (const int*)d_in[2];
    const float* w_ih      = (const float*)d_in[3];
    const float* w_hh      = (const float*)d_in[4];
    const float* b_ih      = (const float*)d_in[5];
    const float* b_hh      = (const float*)d_in[6];
    float* out = (float*)d_out;

    // workspace layout (ints, ~13.6 MB)
    int* ws      = (int*)d_ws;
    int* count   = ws;                       // 100000
    int* offsets = ws + N_NODES_C;           // 100000
    int* rank    = ws + 2 * N_NODES_C;       // 1.6M
    int* perm    = rank + N_EDGES_C;         // 1.6M
    int* bsums   = perm + N_EDGES_C;         // 128

    hipMemsetAsync(count, 0, N_NODES_C * sizeof(int), stream);

    hist_kernel<<<(N_EDGES_C + 255) / 256, 256, 0, stream>>>(receivers, count, rank);
    scan1_kernel<<<N_SCAN_BLOCKS, SCAN_B, 0, stream>>>(count, offsets, bsums);
    scan2_kernel<<<1, 128, 0, stream>>>(bsums);
    permw_kernel<<<(N_EDGES_C + 255) / 256, 256, 0, stream>>>(receivers, offsets, bsums, rank, perm);

    // aggr lives in d_out; gru_kernel consumes and overwrites it in place.
    gather_kernel<<<(N_NODES_C + 3) / 4, 256, 0, stream>>>(edges, perm, offsets, bsums, count, out);
    gru_kernel<<<N_NODES_C / NT, 256, 0, stream>>>(out, nodes, w_ih, w_hh, b_ih, b_hh);
}

// Round 8
// 245.154 us; speedup vs baseline: 1.4156x; 1.3192x over previous
//
#include <hip/hip_runtime.h>
#include <math.h>

#define N_NODES_C 100000
#define N_EDGES_C 1600000
#define DIM 64
#define G3 192
#define SCAN_B 1024
#define N_SCAN_BLOCKS ((N_NODES_C + SCAN_B - 1) / SCAN_B)   // 98

typedef short bf16x8 __attribute__((ext_vector_type(8)));
typedef float f32x4 __attribute__((ext_vector_type(4)));

// ---------------------------------------------------------------------------
// Phase 1a: histogram receivers, record per-edge rank within its segment
// ---------------------------------------------------------------------------
__global__ void hist_kernel(const int* __restrict__ receivers,
                            int* __restrict__ count,
                            int* __restrict__ rank) {
    int e = blockIdx.x * blockDim.x + threadIdx.x;
    if (e >= N_EDGES_C) return;
    int r = receivers[e];
    rank[e] = __hip_atomic_fetch_add(&count[r], 1,
                                     __ATOMIC_RELAXED, __HIP_MEMORY_SCOPE_AGENT);
}

// ---------------------------------------------------------------------------
// Phase 1b: scan. offsets[] = block-local exclusive; bsums[] = per-block base
// ---------------------------------------------------------------------------
__global__ void scan1_kernel(const int* __restrict__ count,
                             int* __restrict__ offsets,
                             int* __restrict__ bsums) {
    __shared__ int wsum[16];
    const int gid  = blockIdx.x * SCAN_B + threadIdx.x;
    const int lane = threadIdx.x & 63;
    const int wv   = threadIdx.x >> 6;
    int c = (gid < N_NODES_C) ? count[gid] : 0;
    int x = c;
    #pragma unroll
    for (int o = 1; o < 64; o <<= 1) {
        int v = __shfl_up(x, o);
        if (lane >= o) x += v;
    }
    if (lane == 63) wsum[wv] = x;
    __syncthreads();
    if (wv == 0) {
        int s = (lane < 16) ? wsum[lane] : 0;
        #pragma unroll
        for (int o = 1; o < 16; o <<= 1) {
            int v = __shfl_up(s, o);
            if (lane >= o) s += v;
        }
        if (lane < 16) wsum[lane] = s;   // inclusive over waves
    }
    __syncthreads();
    int woff = (wv == 0) ? 0 : wsum[wv - 1];
    if (gid < N_NODES_C) offsets[gid] = woff + x - c;
    if (threadIdx.x == SCAN_B - 1) bsums[blockIdx.x] = wsum[15];
}

__global__ void scan2_kernel(int* __restrict__ bsums) {
    __shared__ int w0tot;
    const int i    = threadIdx.x;
    const int lane = threadIdx.x & 63;
    const int wv   = threadIdx.x >> 6;
    int c = (i < N_SCAN_BLOCKS) ? bsums[i] : 0;
    int x = c;
    #pragma unroll
    for (int o = 1; o < 64; o <<= 1) {
        int v = __shfl_up(x, o);
        if (lane >= o) x += v;
    }
    if (wv == 0 && lane == 63) w0tot = x;
    __syncthreads();
    int add = (wv == 1) ? w0tot : 0;
    if (i < N_SCAN_BLOCKS) bsums[i] = add + x - c;   // exclusive
}

// ---------------------------------------------------------------------------
// Phase 1c: write permutation (CSR edge lists); bsums applied inline
// ---------------------------------------------------------------------------
__global__ void permw_kernel(const int* __restrict__ receivers,
                             const int* __restrict__ offsets,
                             const int* __restrict__ bsums,
                             const int* __restrict__ rank,
                             int* __restrict__ perm) {
    int e = blockIdx.x * blockDim.x + threadIdx.x;
    if (e >= N_EDGES_C) return;
    int r = receivers[e];
    perm[offsets[r] + bsums[r >> 10] + rank[e]] = e;
}

// ---------------------------------------------------------------------------
// Phase 2: gather-aggregate (round-7 form, at the random-read ceiling)
// ---------------------------------------------------------------------------
__global__ __launch_bounds__(256)
void gather_kernel(const float* __restrict__ edges,
                   const int* __restrict__ perm,
                   const int* __restrict__ offsets,
                   const int* __restrict__ bsums,
                   const int* __restrict__ count,
                   float* __restrict__ aggr) {
    const int w    = (blockIdx.x << 2) | (threadIdx.x >> 6);
    const int lane = threadIdx.x & 63;
    if (w >= N_NODES_C) return;
    const int g    = lane >> 4;
    const int c4   = (lane & 15) << 2;
    const int start = offsets[w] + bsums[w >> 10];
    const int cnt   = count[w];

    float4 a0 = make_float4(0.f, 0.f, 0.f, 0.f);
    float4 a1 = a0, a2 = a0, a3 = a0;

    int done = 0;
    while (done < cnt) {
        const int pv  = perm[start + min(done + lane, cnt - 1)];
        const int lim = min(cnt - done, 64);
        const int nq  = (lim + 15) >> 4;
        for (int q = 0; q < nq; ++q) {
            const int rbase = q << 4;
            #pragma unroll
            for (int b = 0; b < 4; ++b) {
                const int rr  = rbase + (b << 2) + g;
                const int src = min(rr, lim - 1);
                const int e   = __shfl(pv, src);
                const float4 v = *reinterpret_cast<const float4*>(
                    edges + (size_t)e * DIM + c4);
                const float m = (rr < lim) ? 1.f : 0.f;
                if (b == 0) { a0.x += v.x*m; a0.y += v.y*m; a0.z += v.z*m; a0.w += v.w*m; }
                if (b == 1) { a1.x += v.x*m; a1.y += v.y*m; a1.z += v.z*m; a1.w += v.w*m; }
                if (b == 2) { a2.x += v.x*m; a2.y += v.y*m; a2.z += v.z*m; a2.w += v.w*m; }
                if (b == 3) { a3.x += v.x*m; a3.y += v.y*m; a3.z += v.z*m; a3.w += v.w*m; }
            }
        }
        done += 64;
    }

    float4 s;
    s.x = (a0.x + a1.x) + (a2.x + a3.x);
    s.y = (a0.y + a1.y) + (a2.y + a3.y);
    s.z = (a0.z + a1.z) + (a2.z + a3.z);
    s.w = (a0.w + a1.w) + (a2.w + a3.w);
    #pragma unroll
    for (int m = 16; m <= 32; m <<= 1) {
        s.x += __shfl_xor(s.x, m);
        s.y += __shfl_xor(s.y, m);
        s.z += __shfl_xor(s.z, m);
        s.w += __shfl_xor(s.w, m);
    }
    if (lane < 16) {
        *reinterpret_cast<float4*>(aggr + (size_t)w * DIM + c4) = s;
    }
}

// ---------------------------------------------------------------------------
// Phase 3: GRU via MFMA, split-bf16 (hi/lo), 3 products per tile.
// Block = 256 thr / 64 nodes; wave tile = 16 rows x 192 cols.
// mfma_f32_16x16x32_bf16: A row=lane&15, k=8*(lane>>4)+j; B col=lane&15,
// same k; D col=lane&15, row=(lane>>4)*4+reg (m89-verified).
// LDS: weights bf16 hi/lo 48KB (XOR-swizzled 16B chunks) + rows 16KB = 64KB.
// ---------------------------------------------------------------------------
__device__ __forceinline__ unsigned short bf16_rne(float f) {
    unsigned int u = __float_as_uint(f);
    return (unsigned short)((u + 0x7FFFu + ((u >> 16) & 1u)) >> 16);
}

__device__ __forceinline__ void stage_w(const float* __restrict__ w,
                                        unsigned short* whi,
                                        unsigned short* wlo, int tid) {
    #pragma unroll
    for (int i = 0; i < 6; ++i) {
        const int ci  = tid + i * 256;        // chunk id, 1536 total
        const int col = ci >> 3;
        const int ch  = ci & 7;
        const float4 f0 = *reinterpret_cast<const float4*>(w + col * 64 + ch * 8);
        const float4 f1 = *reinterpret_cast<const float4*>(w + col * 64 + ch * 8 + 4);
        const float f[8] = {f0.x, f0.y, f0.z, f0.w, f1.x, f1.y, f1.z, f1.w};
        unsigned int hi[4], lo[4];
        #pragma unroll
        for (int j = 0; j < 4; ++j) {
            const unsigned int u0 = __float_as_uint(f[2 * j]);
            const unsigned int u1 = __float_as_uint(f[2 * j + 1]);
            const float l0 = f[2 * j]     - __uint_as_float(u0 & 0xFFFF0000u);
            const float l1 = f[2 * j + 1] - __uint_as_float(u1 & 0xFFFF0000u);
            hi[j] = (u0 >> 16) | ((u1 >> 16) << 16);
            lo[j] = (unsigned int)bf16_rne(l0) | ((unsigned int)bf16_rne(l1) << 16);
        }
        const int addr = col * 64 + ((ch ^ (col & 7)) << 3);   // ushort units
        *reinterpret_cast<uint4*>(whi + addr) = make_uint4(hi[0], hi[1], hi[2], hi[3]);
        *reinterpret_cast<uint4*>(wlo + addr) = make_uint4(lo[0], lo[1], lo[2], lo[3]);
    }
}

__device__ __forceinline__ void stage_rows(const float* __restrict__ src,
                                           float* rows, int nb, int tid) {
    #pragma unroll
    for (int i = 0; i < 4; ++i) {
        const int idx = tid + i * 256;        // 1024 float4
        const int r = idx >> 4, c = idx & 15;
        float4 v = make_float4(0.f, 0.f, 0.f, 0.f);
        if (nb + r < N_NODES_C)
            v = *reinterpret_cast<const float4*>(src + (size_t)(nb + r) * 64 + (c << 2));
        *reinterpret_cast<float4*>(rows + r * 64 + ((c ^ (r & 15)) << 2)) = v;
    }
}

__global__ __launch_bounds__(256, 2)
void gru_mfma_kernel(float* aggr_out,                  // d_out: aggr in, result out
                     const float* __restrict__ nodes,
                     const float* __restrict__ w_ih,
                     const float* __restrict__ w_hh,
                     const float* __restrict__ b_ih,
                     const float* __restrict__ b_hh) {
    __shared__ __align__(16) unsigned short s_w[2 * 12288];  // hi | lo, 48 KB
    __shared__ __align__(16) float s_rows[64 * 64];          // 16 KB

    const int tid  = threadIdx.x;
    const int lane = tid & 63;
    const int wave = tid >> 6;
    const int nb   = blockIdx.x * 64;
    const int l15  = lane & 15;
    const int lg   = lane >> 4;

    // bias preload (o = l15 + 16t per gate)
    float bir[4], biz[4], bin_[4], bhr[4], bhz[4], bhn[4];
    #pragma unroll
    for (int t = 0; t < 4; ++t) {
        const int o = l15 + (t << 4);
        bir[t] = b_ih[o]; biz[t] = b_ih[64 + o]; bin_[t] = b_ih[128 + o];
        bhr[t] = b_hh[o]; bhz[t] = b_hh[64 + o]; bhn[t] = b_hh[128 + o];
    }

    f32x4 accA[12], accB[12];
    #pragma unroll
    for (int ct = 0; ct < 12; ++ct) { accA[ct] = (f32x4)(0.f); accB[ct] = (f32x4)(0.f); }

    unsigned short* whi = s_w;
    unsigned short* wlo = s_w + 12288;
    const int arow = (wave << 4) + l15;     // A row for this lane

    // ================= GEMM 1: gi = aggr @ w_ih.T =================
    stage_w(w_ih, whi, wlo, tid);
    stage_rows(aggr_out, s_rows, nb, tid);
    __syncthreads();

    #pragma unroll
    for (int kt = 0; kt < 2; ++kt) {
        // A fragment (hi/lo) from swizzled rows
        const int c0 = kt * 8 + (lg << 1);
        const float4 fa = *reinterpret_cast<const float4*>(
            &s_rows[arow * 64 + ((c0 ^ l15) << 2)]);
        const float4 fb = *reinterpret_cast<const float4*>(
            &s_rows[arow * 64 + (((c0 + 1) ^ l15) << 2)]);
        const float f[8] = {fa.x, fa.y, fa.z, fa.w, fb.x, fb.y, fb.z, fb.w};
        union { bf16x8 v; unsigned int u[4]; } ahi, alo;
        #pragma unroll
        for (int j = 0; j < 4; ++j) {
            const unsigned int u0 = __float_as_uint(f[2 * j]);
            const unsigned int u1 = __float_as_uint(f[2 * j + 1]);
            const float l0 = f[2 * j]     - __uint_as_float(u0 & 0xFFFF0000u);
            const float l1 = f[2 * j + 1] - __uint_as_float(u1 & 0xFFFF0000u);
            ahi.u[j] = (u0 >> 16) | ((u1 >> 16) << 16);
            alo.u[j] = (unsigned int)bf16_rne(l0) | ((unsigned int)bf16_rne(l1) << 16);
        }
        #pragma unroll
        for (int ct = 0; ct < 12; ++ct) {
            const int col = ct * 16 + l15;
            const int sw  = (kt * 4 + lg) ^ (col & 7);
            const bf16x8 bhi = *reinterpret_cast<const bf16x8*>(&whi[col * 64 + (sw << 3)]);
            const bf16x8 blo = *reinterpret_cast<const bf16x8*>(&wlo[col * 64 + (sw << 3)]);
            accA[ct] = __builtin_amdgcn_mfma_f32_16x16x32_bf16(ahi.v, bhi, accA[ct], 0, 0, 0);
            accA[ct] = __builtin_amdgcn_mfma_f32_16x16x32_bf16(alo.v, bhi, accA[ct], 0, 0, 0);
            accA[ct] = __builtin_amdgcn_mfma_f32_16x16x32_bf16(ahi.v, blo, accA[ct], 0, 0, 0);
        }
    }
    __syncthreads();

    // ================= GEMM 2: gh = nodes @ w_hh.T =================
    stage_w(w_hh, whi, wlo, tid);
    stage_rows(nodes, s_rows, nb, tid);
    __syncthreads();

    #pragma unroll
    for (int kt = 0; kt < 2; ++kt) {
        const int c0 = kt * 8 + (lg << 1);
        const float4 fa = *reinterpret_cast<const float4*>(
            &s_rows[arow * 64 + ((c0 ^ l15) << 2)]);
        const float4 fb = *reinterpret_cast<const float4*>(
            &s_rows[arow * 64 + (((c0 + 1) ^ l15) << 2)]);
        const float f[8] = {fa.x, fa.y, fa.z, fa.w, fb.x, fb.y, fb.z, fb.w};
        union { bf16x8 v; unsigned int u[4]; } ahi, alo;
        #pragma unroll
        for (int j = 0; j < 4; ++j) {
            const unsigned int u0 = __float_as_uint(f[2 * j]);
            const unsigned int u1 = __float_as_uint(f[2 * j + 1]);
            const float l0 = f[2 * j]     - __uint_as_float(u0 & 0xFFFF0000u);
            const float l1 = f[2 * j + 1] - __uint_as_float(u1 & 0xFFFF0000u);
            ahi.u[j] = (u0 >> 16) | ((u1 >> 16) << 16);
            alo.u[j] = (unsigned int)bf16_rne(l0) | ((unsigned int)bf16_rne(l1) << 16);
        }
        #pragma unroll
        for (int ct = 0; ct < 12; ++ct) {
            const int col = ct * 16 + l15;
            const int sw  = (kt * 4 + lg) ^ (col & 7);
            const bf16x8 bhi = *reinterpret_cast<const bf16x8*>(&whi[col * 64 + (sw << 3)]);
            const bf16x8 blo = *reinterpret_cast<const bf16x8*>(&wlo[col * 64 + (sw << 3)]);
            accB[ct] = __builtin_amdgcn_mfma_f32_16x16x32_bf16(ahi.v, bhi, accB[ct], 0, 0, 0);
            accB[ct] = __builtin_amdgcn_mfma_f32_16x16x32_bf16(alo.v, bhi, accB[ct], 0, 0, 0);
            accB[ct] = __builtin_amdgcn_mfma_f32_16x16x32_bf16(ahi.v, blo, accB[ct], 0, 0, 0);
        }
    }

    // ================= gates + store (s_rows still holds node rows) ========
    #pragma unroll
    for (int t = 0; t < 4; ++t) {
        #pragma unroll
        for (int rg = 0; rg < 4; ++rg) {
            const int rr   = (wave << 4) + (lg << 2) + rg;   // row in block
            const int node = nb + rr;
            const int o    = l15 + (t << 4);
            const float ir = accA[t][rg]     + bir[t];
            const float iz = accA[4 + t][rg] + biz[t];
            const float inn= accA[8 + t][rg] + bin_[t];
            const float hr = accB[t][rg]     + bhr[t];
            const float hz = accB[4 + t][rg] + bhz[t];
            const float hn = accB[8 + t][rg] + bhn[t];
            const float r = 1.f / (1.f + __expf(-(ir + hr)));
            const float z = 1.f / (1.f + __expf(-(iz + hz)));
            float tt = inn + r * hn;
            tt = fminf(fmaxf(tt, -15.f), 15.f);
            const float e2 = __expf(2.f * tt);
            const float ng = (e2 - 1.f) / (e2 + 1.f);
            const int c = o >> 2;
            const float h = s_rows[rr * 64 + ((c ^ (rr & 15)) << 2) + (o & 3)];
            if (node < N_NODES_C)
                aggr_out[(size_t)node * 64 + o] = (1.f - z) * ng + z * h;
        }
    }
}

// ---------------------------------------------------------------------------
extern "C" void kernel_launch(void* const* d_in, const int* in_sizes, int n_in,
                              void* d_out, int out_size, void* d_ws, size_t ws_size,
                              hipStream_t stream) {
    const float* edges     = (const float*)d_in[0];
    const float* nodes     = (const float*)d_in[1];
    const int*   receivers = (const int*)d_in[2];
    const float* w_ih      = (const float*)d_in[3];
    const float* w_hh      = (const float*)d_in[4];
    const float* b_ih      = (const float*)d_in[5];
    const float* b_hh      = (const float*)d_in[6];
    float* out = (float*)d_out;

    // workspace layout (ints, ~13.6 MB)
    int* ws      = (int*)d_ws;
    int* count   = ws;                       // 100000
    int* offsets = ws + N_NODES_C;           // 100000
    int* rank    = ws + 2 * N_NODES_C;       // 1.6M
    int* perm    = rank + N_EDGES_C;         // 1.6M
    int* bsums   = perm + N_EDGES_C;         // 128

    hipMemsetAsync(count, 0, N_NODES_C * sizeof(int), stream);

    hist_kernel<<<(N_EDGES_C + 255) / 256, 256, 0, stream>>>(receivers, count, rank);
    scan1_kernel<<<N_SCAN_BLOCKS, SCAN_B, 0, stream>>>(count, offsets, bsums);
    scan2_kernel<<<1, 128, 0, stream>>>(bsums);
    permw_kernel<<<(N_EDGES_C + 255) / 256, 256, 0, stream>>>(receivers, offsets, bsums, rank, perm);

    // aggr lives in d_out; gru kernel consumes and overwrites it in place.
    gather_kernel<<<(N_NODES_C + 3) / 4, 256, 0, stream>>>(edges, perm, offsets, bsums, count, out);
    gru_mfma_kernel<<<(N_NODES_C + 63) / 64, 256, 0, stream>>>(out, nodes, w_ih, w_hh, b_ih, b_hh);
}